// Round 2
// baseline (1188.828 us; speedup 1.0000x reference)
//
#include <hip/hip_runtime.h>

// (B, CQ, CR, HID, H, W) = (8, 1024, 512, 256, 48, 48)
#define BB   8
#define PP   2304
#define CQD  1024
#define CRD  512
#define HIDD 256
#define KC   3        // split-K chunks in attention
#define KPC  768      // keys per chunk (PP/KC)
#define QT   72       // q-tiles per batch (PP/32)

typedef float f32x4 __attribute__((ext_vector_type(4)));
typedef __bf16 bf16x8 __attribute__((ext_vector_type(8)));
typedef unsigned short u16x8 __attribute__((ext_vector_type(8)));
typedef unsigned short u16x4 __attribute__((ext_vector_type(4)));
typedef unsigned short ushort_t;

__device__ __forceinline__ unsigned short f2bf(float f) {
  unsigned int u = __float_as_uint(f);
  u += 0x7fffu + ((u >> 16) & 1u);  // RNE
  return (unsigned short)(u >> 16);
}
__device__ __forceinline__ float bf2f(unsigned short h) {
  return __uint_as_float(((unsigned int)h) << 16);
}
__device__ __forceinline__ bf16x8 load_bf8(const ushort_t* p) {
  return *(const bf16x8*)p;
}

#define MFMA16(a, b, c) __builtin_amdgcn_mfma_f32_16x16x32_bf16((a), (b), (c), 0, 0, 0)

// ---------------------------------------------------------------------------
// Transpose + hi/lo split: fp32 [b][C][PP] -> bf16 [b][PP][C] (hi, lo)
// ---------------------------------------------------------------------------
template <int C>
__global__ __launch_bounds__(256) void tsplit_kernel(
    const float* __restrict__ X, ushort_t* __restrict__ Th,
    ushort_t* __restrict__ Tl) {
  const int b = blockIdx.z;
  const int c0 = blockIdx.y * 32;
  const int p0 = blockIdx.x * 64;
  const int tid = threadIdx.x;
  __shared__ float T[32][65];

  {
    const int c = tid >> 3;
    const int pb = (tid & 7) * 8;
    const float* src = X + ((size_t)b * C + c0 + c) * PP + p0 + pb;
    float4 v0 = *(const float4*)src;
    float4 v1 = *(const float4*)(src + 4);
    T[c][pb + 0] = v0.x; T[c][pb + 1] = v0.y; T[c][pb + 2] = v0.z; T[c][pb + 3] = v0.w;
    T[c][pb + 4] = v1.x; T[c][pb + 5] = v1.y; T[c][pb + 6] = v1.z; T[c][pb + 7] = v1.w;
  }
  __syncthreads();
  {
    const int p = tid >> 2;
    const int cb = (tid & 3) * 8;
    u16x8 h, l;
#pragma unroll
    for (int j = 0; j < 8; ++j) {
      float f = T[cb + j][p];
      unsigned short hh = f2bf(f);
      h[j] = hh;
      l[j] = f2bf(f - bf2f(hh));
    }
    const size_t o = ((size_t)b * PP + p0 + p) * C + c0 + cb;
    *(u16x8*)(Th + o) = h;
    *(u16x8*)(Tl + o) = l;
  }
}

// ---------------------------------------------------------------------------
// Elementwise hi/lo split of W (fp32 -> bf16 hi, lo)
// ---------------------------------------------------------------------------
__global__ void wsplit_kernel(const float* __restrict__ W,
                              ushort_t* __restrict__ Wh,
                              ushort_t* __restrict__ Wl) {
  const int i = blockIdx.x * 256 + threadIdx.x;
  float f = W[i];
  unsigned short h = f2bf(f);
  Wh[i] = h;
  Wl[i] = f2bf(f - bf2f(h));
}

// ---------------------------------------------------------------------------
// V cast: fp32 [b][c][p] -> bf16 same layout
// ---------------------------------------------------------------------------
__global__ void cast_v_kernel(const float* __restrict__ X,
                              ushort_t* __restrict__ V) {
  const size_t i = ((size_t)blockIdx.x * 256 + threadIdx.x) * 4;
  float4 v = *(const float4*)(X + i);
  u16x4 o;
  o[0] = f2bf(v.x); o[1] = f2bf(v.y); o[2] = f2bf(v.z); o[3] = f2bf(v.w);
  *(u16x4*)(V + i) = o;
}

// ---------------------------------------------------------------------------
// Projection v2 (pre-split inputs): barrier-free, fragments from global.
// Out[b][p][o] = sum_c W[o][c] X[b][p][c] + bias[o]; hi/lo bf16 out [b][p][HID]
// ---------------------------------------------------------------------------
template <int C>
__global__ __launch_bounds__(256) void proj2_kernel(
    const ushort_t* __restrict__ XTh, const ushort_t* __restrict__ XTl,
    const ushort_t* __restrict__ Wh, const ushort_t* __restrict__ Wl,
    const float* __restrict__ bias, ushort_t* __restrict__ Oh,
    ushort_t* __restrict__ Ol) {
  const int b = blockIdx.z;
  const int p0 = blockIdx.y * 64;
  const int o0 = blockIdx.x * 64;
  const int tid = threadIdx.x;
  const int lane = tid & 63;
  const int wave = tid >> 6;
  const int wm = wave & 1;
  const int wn = wave >> 1;
  const int l15 = lane & 15;
  const int quad = lane >> 4;

  f32x4 acc[2][2] = {};

  const size_t wrow0 = (size_t)(o0 + wm * 32 + l15) * C;
  const size_t wrow1 = wrow0 + (size_t)16 * C;
  const size_t xrow0 = ((size_t)b * PP + p0 + wn * 32 + l15) * C;
  const size_t xrow1 = xrow0 + (size_t)16 * C;

  for (int c0 = 0; c0 < C; c0 += 64) {
#pragma unroll
    for (int ks = 0; ks < 2; ++ks) {
      const int kk = c0 + ks * 32 + quad * 8;
      bf16x8 wh0 = load_bf8(Wh + wrow0 + kk);
      bf16x8 wl0 = load_bf8(Wl + wrow0 + kk);
      bf16x8 wh1 = load_bf8(Wh + wrow1 + kk);
      bf16x8 wl1 = load_bf8(Wl + wrow1 + kk);
      bf16x8 xh0 = load_bf8(XTh + xrow0 + kk);
      bf16x8 xl0 = load_bf8(XTl + xrow0 + kk);
      bf16x8 xh1 = load_bf8(XTh + xrow1 + kk);
      bf16x8 xl1 = load_bf8(XTl + xrow1 + kk);

      acc[0][0] = MFMA16(wh0, xh0, acc[0][0]);
      acc[0][0] = MFMA16(wl0, xh0, acc[0][0]);
      acc[0][0] = MFMA16(wh0, xl0, acc[0][0]);
      acc[1][0] = MFMA16(wh1, xh0, acc[1][0]);
      acc[1][0] = MFMA16(wl1, xh0, acc[1][0]);
      acc[1][0] = MFMA16(wh1, xl0, acc[1][0]);
      acc[0][1] = MFMA16(wh0, xh1, acc[0][1]);
      acc[0][1] = MFMA16(wl0, xh1, acc[0][1]);
      acc[0][1] = MFMA16(wh0, xl1, acc[0][1]);
      acc[1][1] = MFMA16(wh1, xh1, acc[1][1]);
      acc[1][1] = MFMA16(wl1, xh1, acc[1][1]);
      acc[1][1] = MFMA16(wh1, xl1, acc[1][1]);
    }
  }

#pragma unroll
  for (int mt = 0; mt < 2; ++mt) {
    const int ob = o0 + wm * 32 + mt * 16 + quad * 4;
#pragma unroll
    for (int nt = 0; nt < 2; ++nt) {
      const int p = p0 + wn * 32 + nt * 16 + l15;
      u16x4 hs, ls;
#pragma unroll
      for (int r = 0; r < 4; ++r) {
        float v = acc[mt][nt][r] + bias[ob + r];
        unsigned short h = f2bf(v);
        hs[r] = h;
        ls[r] = f2bf(v - bf2f(h));
      }
      const size_t base = ((size_t)b * PP + p) * HIDD + ob;
      *(u16x4*)(Oh + base) = hs;
      *(u16x4*)(Ol + base) = ls;
    }
  }
}

// ---------------------------------------------------------------------------
// Legacy projection (fp32 inputs, in-kernel split) — ws-too-small fallback
// ---------------------------------------------------------------------------
template <int C>
__global__ __launch_bounds__(256) void proj_legacy_kernel(
    const float* __restrict__ X, const float* __restrict__ W,
    const float* __restrict__ bias, ushort_t* __restrict__ Oh,
    ushort_t* __restrict__ Ol) {
  const int b = blockIdx.z;
  const int p0 = blockIdx.y * 64;
  const int o0 = blockIdx.x * 64;
  const int tid = threadIdx.x;
  const int lane = tid & 63;
  const int wave = tid >> 6;
  const int wm = wave & 1;
  const int wn = wave >> 1;
  const int l15 = lane & 15;
  const int quad = lane >> 4;

  __shared__ ushort_t Xh[64][40];
  __shared__ ushort_t Xl[64][40];

  f32x4 acc[2][2] = {};
  const float* Xb = X + (size_t)b * C * PP;
  const int cc = tid >> 3;
  const int ppo = (tid & 7) * 8;

  for (int c0 = 0; c0 < C; c0 += 32) {
    const float* src = Xb + (size_t)(c0 + cc) * PP + p0 + ppo;
    float4 v0 = *(const float4*)(src);
    float4 v1 = *(const float4*)(src + 4);
    float vv[8] = {v0.x, v0.y, v0.z, v0.w, v1.x, v1.y, v1.z, v1.w};
#pragma unroll
    for (int j = 0; j < 8; ++j) {
      unsigned short h = f2bf(vv[j]);
      Xh[ppo + j][cc] = h;
      Xl[ppo + j][cc] = f2bf(vv[j] - bf2f(h));
    }
    __syncthreads();

    bf16x8 wh[2], wl[2];
#pragma unroll
    for (int mt = 0; mt < 2; ++mt) {
      const float* wsrc =
          W + (size_t)(o0 + wm * 32 + mt * 16 + l15) * C + c0 + quad * 8;
      float4 a0 = *(const float4*)(wsrc);
      float4 a1 = *(const float4*)(wsrc + 4);
      float av[8] = {a0.x, a0.y, a0.z, a0.w, a1.x, a1.y, a1.z, a1.w};
      u16x8 hh, ll;
#pragma unroll
      for (int j = 0; j < 8; ++j) {
        unsigned short h = f2bf(av[j]);
        hh[j] = h;
        ll[j] = f2bf(av[j] - bf2f(h));
      }
      wh[mt] = __builtin_bit_cast(bf16x8, hh);
      wl[mt] = __builtin_bit_cast(bf16x8, ll);
    }

#pragma unroll
    for (int nt = 0; nt < 2; ++nt) {
      const int pr = wn * 32 + nt * 16 + l15;
      bf16x8 xh = load_bf8(&Xh[pr][quad * 8]);
      bf16x8 xl = load_bf8(&Xl[pr][quad * 8]);
#pragma unroll
      for (int mt = 0; mt < 2; ++mt) {
        acc[mt][nt] = MFMA16(wh[mt], xh, acc[mt][nt]);
        acc[mt][nt] = MFMA16(wl[mt], xh, acc[mt][nt]);
        acc[mt][nt] = MFMA16(wh[mt], xl, acc[mt][nt]);
      }
    }
    __syncthreads();
  }

#pragma unroll
  for (int mt = 0; mt < 2; ++mt) {
    const int ob = o0 + wm * 32 + mt * 16 + quad * 4;
#pragma unroll
    for (int nt = 0; nt < 2; ++nt) {
      const int p = p0 + wn * 32 + nt * 16 + l15;
      u16x4 hs, ls;
#pragma unroll
      for (int r = 0; r < 4; ++r) {
        float v = acc[mt][nt][r] + bias[ob + r];
        unsigned short h = f2bf(v);
        hs[r] = h;
        ls[r] = f2bf(v - bf2f(h));
      }
      const size_t base = ((size_t)b * PP + p) * HIDD + ob;
      *(u16x4*)(Oh + base) = hs;
      *(u16x4*)(Ol + base) = ls;
    }
  }
}

// ---------------------------------------------------------------------------
// Flash attention v2: split-K, Q from global (no preload), 2 barriers/tile.
// DIRECT: single chunk, normalize + write fp32 out.
// else:   write unnormalized O (bf16, [c][q]) + (m,l) partials.
// ---------------------------------------------------------------------------
template <bool DIRECT>
__global__ __launch_bounds__(256, 4) void attn2_kernel(
    const ushort_t* __restrict__ Qh, const ushort_t* __restrict__ Ql,
    const ushort_t* __restrict__ Kh, const ushort_t* __restrict__ Kl,
    const ushort_t* __restrict__ Vb, float* __restrict__ out,
    ushort_t* __restrict__ Opart, float* __restrict__ mlbuf, int kpc) {
  const int b = blockIdx.z;
  const int qt = blockIdx.x;
  const int kc = blockIdx.y;
  const int q0 = qt * 32;
  const int k0 = kc * kpc;
  const int tid = threadIdx.x;
  const int lane = tid & 63;
  const int wave = tid >> 6;
  const int l15 = lane & 15;
  const int quad = lane >> 4;

  __shared__ float S_lds[2][32][73];      // stride 73 dwords: <=2-way banks
  __shared__ ushort_t P_lds[2][32][72];   // 16B-aligned rows for b128 reads
  __shared__ float m_state[32], l_state[32], a_state[32];

  if (tid < 32) {
    m_state[tid] = -3.0e38f;
    l_state[tid] = 0.f;
  }

  f32x4 o_acc[2][8] = {};
  const int srow = tid >> 3;
  const int scol = (tid & 7) * 8;

  const size_t qrow0 = ((size_t)b * PP + q0 + l15) * HIDD;
  const size_t qrow1 = qrow0 + (size_t)16 * HIDD;

  __syncthreads();
  int buf = 0;

  for (int kt = 0; kt < kpc; kt += 64) {
    // ---- S = Qh*Kh + Ql*Kh + Qh*Kl, wave's 16-key slice ----
    f32x4 s0 = {}, s1 = {};
    const size_t krow = ((size_t)b * PP + k0 + kt + wave * 16 + l15) * HIDD;
#pragma unroll
    for (int ks = 0; ks < 8; ++ks) {
      const int o = ks * 32 + quad * 8;
      bf16x8 kh = load_bf8(Kh + krow + o);
      bf16x8 kl = load_bf8(Kl + krow + o);
      bf16x8 q0h = load_bf8(Qh + qrow0 + o);
      bf16x8 q0l = load_bf8(Ql + qrow0 + o);
      bf16x8 q1h = load_bf8(Qh + qrow1 + o);
      bf16x8 q1l = load_bf8(Ql + qrow1 + o);
      s0 = MFMA16(q0h, kh, s0);
      s1 = MFMA16(q1h, kh, s1);
      s0 = MFMA16(q0l, kh, s0);
      s1 = MFMA16(q1l, kh, s1);
      s0 = MFMA16(q0h, kl, s0);
      s1 = MFMA16(q1h, kl, s1);
    }
#pragma unroll
    for (int r = 0; r < 4; ++r) {
      S_lds[buf][quad * 4 + r][wave * 16 + l15] = s0[r];
      S_lds[buf][16 + quad * 4 + r][wave * 16 + l15] = s1[r];
    }
    __syncthreads();

    // ---- online softmax (8 threads / q-row) ----
    {
      float v[8];
#pragma unroll
      for (int j = 0; j < 8; ++j) v[j] = S_lds[buf][srow][scol + j];
      float mx = v[0];
#pragma unroll
      for (int j = 1; j < 8; ++j) mx = fmaxf(mx, v[j]);
      mx = fmaxf(mx, __shfl_xor(mx, 1));
      mx = fmaxf(mx, __shfl_xor(mx, 2));
      mx = fmaxf(mx, __shfl_xor(mx, 4));
      const float mold = m_state[srow];
      const float mnew = fmaxf(mold, mx);
      const float alpha = __expf(mold - mnew);
      float ssum = 0.f;
#pragma unroll
      for (int j = 0; j < 8; ++j) {
        float p = __expf(v[j] - mnew);
        ssum += p;
        P_lds[buf][srow][scol + j] = f2bf(p);
      }
      ssum += __shfl_xor(ssum, 1);
      ssum += __shfl_xor(ssum, 2);
      ssum += __shfl_xor(ssum, 4);
      if ((tid & 7) == 0) {
        m_state[srow] = mnew;
        l_state[srow] = l_state[srow] * alpha + ssum;
        a_state[srow] = alpha;
      }
    }
    __syncthreads();

    // ---- rescale + PV ----
    float alph[2][4];
#pragma unroll
    for (int mt = 0; mt < 2; ++mt)
#pragma unroll
      for (int r = 0; r < 4; ++r)
        alph[mt][r] = a_state[mt * 16 + quad * 4 + r];
#pragma unroll
    for (int mt = 0; mt < 2; ++mt)
#pragma unroll
      for (int nt = 0; nt < 8; ++nt)
#pragma unroll
        for (int r = 0; r < 4; ++r) o_acc[mt][nt][r] *= alph[mt][r];

#pragma unroll
    for (int ks = 0; ks < 2; ++ks) {
      bf16x8 pa0 = load_bf8(&P_lds[buf][l15][ks * 32 + quad * 8]);
      bf16x8 pa1 = load_bf8(&P_lds[buf][16 + l15][ks * 32 + quad * 8]);
#pragma unroll
      for (int nt = 0; nt < 8; ++nt) {
        const int c = wave * 128 + nt * 16 + l15;
        bf16x8 vb = load_bf8(Vb + ((size_t)b * CRD + c) * PP + k0 + kt +
                             ks * 32 + quad * 8);
        o_acc[0][nt] = MFMA16(pa0, vb, o_acc[0][nt]);
        o_acc[1][nt] = MFMA16(pa1, vb, o_acc[1][nt]);
      }
    }
    buf ^= 1;
  }

  if (DIRECT) {
    float rl[2][4];
#pragma unroll
    for (int mt = 0; mt < 2; ++mt)
#pragma unroll
      for (int r = 0; r < 4; ++r)
        rl[mt][r] = 1.f / l_state[mt * 16 + quad * 4 + r];
#pragma unroll
    for (int mt = 0; mt < 2; ++mt)
#pragma unroll
      for (int nt = 0; nt < 8; ++nt) {
        const int c = wave * 128 + nt * 16 + l15;
        f32x4 v = o_acc[mt][nt];
#pragma unroll
        for (int r = 0; r < 4; ++r) v[r] *= rl[mt][r];
        *(f32x4*)(out + ((size_t)b * CRD + c) * PP + q0 + mt * 16 + quad * 4) = v;
      }
  } else {
    const size_t cidx = ((size_t)b * QT + qt) * KC + kc;
#pragma unroll
    for (int mt = 0; mt < 2; ++mt)
#pragma unroll
      for (int nt = 0; nt < 8; ++nt) {
        const int c = wave * 128 + nt * 16 + l15;
        u16x4 hs;
#pragma unroll
        for (int r = 0; r < 4; ++r) hs[r] = f2bf(o_acc[mt][nt][r]);
        *(u16x4*)(Opart + cidx * (CRD * 32) + (size_t)c * 32 + mt * 16 +
                  quad * 4) = hs;
      }
    if (tid < 32) {
      mlbuf[cidx * 64 + tid] = m_state[tid];
      mlbuf[cidx * 64 + 32 + tid] = l_state[tid];
    }
  }
}

// ---------------------------------------------------------------------------
// Combine split-K partials: out = (sum_c w_c * O_c) / (sum_c w_c * l_c)
// ---------------------------------------------------------------------------
__global__ __launch_bounds__(256) void combine_kernel(
    const ushort_t* __restrict__ Opart, const float* __restrict__ mlbuf,
    float* __restrict__ out) {
  const int qt = blockIdx.x;
  const int b = blockIdx.y;
  const int tid = threadIdx.x;
  const int q = tid & 31;
  const int g = tid >> 5;
  const size_t bq = (size_t)b * QT + qt;

  float m[KC], l[KC], w[KC];
#pragma unroll
  for (int c = 0; c < KC; ++c) {
    const size_t base = (bq * KC + c) * 64;
    m[c] = mlbuf[base + q];
    l[c] = mlbuf[base + 32 + q];
  }
  float M = m[0];
#pragma unroll
  for (int c = 1; c < KC; ++c) M = fmaxf(M, m[c]);
  float L = 0.f;
#pragma unroll
  for (int c = 0; c < KC; ++c) {
    w[c] = __expf(m[c] - M);
    L += w[c] * l[c];
  }
  const float inv = 1.f / L;
#pragma unroll
  for (int c = 0; c < KC; ++c) w[c] *= inv;

  for (int ci = 0; ci < 64; ++ci) {
    const int cc = g * 64 + ci;
    float acc = 0.f;
#pragma unroll
    for (int c = 0; c < KC; ++c)
      acc += w[c] * bf2f(Opart[(bq * KC + c) * (CRD * 32) + (size_t)cc * 32 + q]);
    out[((size_t)b * CRD + cc) * PP + qt * 32 + q] = acc;
  }
}

// ---------------------------------------------------------------------------
extern "C" void kernel_launch(void* const* d_in, const int* in_sizes, int n_in,
                              void* d_out, int out_size, void* d_ws,
                              size_t ws_size, hipStream_t stream) {
  (void)in_sizes; (void)n_in; (void)out_size;

  const float* Xq = (const float*)d_in[0];
  const float* Xr = (const float*)d_in[1];
  const float* Wq = (const float*)d_in[2];
  const float* bq = (const float*)d_in[3];
  const float* Wk = (const float*)d_in[4];
  const float* bk = (const float*)d_in[5];
  float* out = (float*)d_out;

  const size_t nQK = (size_t)BB * PP * HIDD;   // 4.72M
  const size_t nV  = (size_t)BB * CRD * PP;    // 9.44M
  const size_t nXq = (size_t)BB * PP * CQD;    // 18.9M
  const size_t nXr = (size_t)BB * PP * CRD;    // 9.44M

  ushort_t* p = (ushort_t*)d_ws;
  ushort_t* Qh = p; p += nQK;
  ushort_t* Ql = p; p += nQK;
  ushort_t* Kh = p; p += nQK;
  ushort_t* Kl = p; p += nQK;
  ushort_t* Vb = p; p += nV;
  ushort_t* XqTh = p; p += nXq;
  ushort_t* XqTl = p; p += nXq;
  ushort_t* XrTh = p; p += nXr;
  ushort_t* XrTl = p; p += nXr;
  ushort_t* Wqh = p; p += (size_t)HIDD * CQD;
  ushort_t* Wql = p; p += (size_t)HIDD * CQD;
  ushort_t* Wkh = p; p += (size_t)HIDD * CRD;
  ushort_t* Wkl = p; p += (size_t)HIDD * CRD;
  const size_t needed = (size_t)((char*)p - (char*)d_ws);

  // split-K partials alias the XqT region (proj_q finishes before attn runs)
  ushort_t* Opart = XqTh;                              // KC*8*72*512*32 u16
  float* mlbuf = (float*)(XqTh + (size_t)KC * BB * QT * CRD * 32);

  if (ws_size >= needed) {
    tsplit_kernel<CQD><<<dim3(PP / 64, CQD / 32, BB), 256, 0, stream>>>(
        Xq, XqTh, XqTl);
    tsplit_kernel<CRD><<<dim3(PP / 64, CRD / 32, BB), 256, 0, stream>>>(
        Xr, XrTh, XrTl);
    wsplit_kernel<<<dim3((HIDD * CQD) / 256), 256, 0, stream>>>(Wq, Wqh, Wql);
    wsplit_kernel<<<dim3((HIDD * CRD) / 256), 256, 0, stream>>>(Wk, Wkh, Wkl);
    cast_v_kernel<<<dim3(nV / 1024), 256, 0, stream>>>(Xr, Vb);
    proj2_kernel<CQD><<<dim3(4, PP / 64, BB), 256, 0, stream>>>(
        XqTh, XqTl, Wqh, Wql, bq, Qh, Ql);
    proj2_kernel<CRD><<<dim3(4, PP / 64, BB), 256, 0, stream>>>(
        XrTh, XrTl, Wkh, Wkl, bk, Kh, Kl);
    attn2_kernel<false><<<dim3(QT, KC, BB), 256, 0, stream>>>(
        Qh, Ql, Kh, Kl, Vb, out, Opart, mlbuf, KPC);
    combine_kernel<<<dim3(QT, BB), 256, 0, stream>>>(Opart, mlbuf, out);
  } else {
    // fallback: round-1 structure (fits in 56.6 MB)
    proj_legacy_kernel<CQD><<<dim3(4, PP / 64, BB), 256, 0, stream>>>(
        Xq, Wq, bq, Qh, Ql);
    proj_legacy_kernel<CRD><<<dim3(4, PP / 64, BB), 256, 0, stream>>>(
        Xr, Wk, bk, Kh, Kl);
    cast_v_kernel<<<dim3(nV / 1024), 256, 0, stream>>>(Xr, Vb);
    attn2_kernel<true><<<dim3(QT, 1, BB), 256, 0, stream>>>(
        Qh, Ql, Kh, Kl, Vb, out, Qh /*unused*/, (float*)Qh /*unused*/, PP);
  }
}

// Round 3
// 1124.786 us; speedup vs baseline: 1.0569x; 1.0569x over previous
//
#include <hip/hip_runtime.h>

// (B, CQ, CR, HID, H, W) = (8, 1024, 512, 256, 48, 48)
#define BB   8
#define PP   2304
#define CQD  1024
#define CRD  512
#define HIDD 256
#define KC   2       // split-K chunks
#define KPC  1152    // keys per chunk
#define NQB  36      // q-blocks (PP/64)

typedef float f32x4 __attribute__((ext_vector_type(4)));
typedef __bf16 bf16x8 __attribute__((ext_vector_type(8)));
typedef unsigned short u16x8 __attribute__((ext_vector_type(8)));
typedef unsigned short u16x4 __attribute__((ext_vector_type(4)));
typedef unsigned short ushort_t;

__device__ __forceinline__ unsigned short f2bf(float f) {
  unsigned int u = __float_as_uint(f);
  u += 0x7fffu + ((u >> 16) & 1u);  // RNE
  return (unsigned short)(u >> 16);
}
__device__ __forceinline__ float bf2f(unsigned short h) {
  return __uint_as_float(((unsigned int)h) << 16);
}
__device__ __forceinline__ bf16x8 load_bf8(const ushort_t* p) {
  return *(const bf16x8*)p;
}
__device__ __forceinline__ void async16(const ushort_t* g, ushort_t* l) {
  __builtin_amdgcn_global_load_lds(
      (const __attribute__((address_space(1))) unsigned int*)g,
      (__attribute__((address_space(3))) unsigned int*)l, 16, 0, 0);
}

#define MFMA16(a, b, c) __builtin_amdgcn_mfma_f32_16x16x32_bf16((a), (b), (c), 0, 0, 0)

// ---------------------------------------------------------------------------
// Projection (round-1, measured): Out[b][p][o] = sum_c W[o][c] X[b][c][p] + b
// hi/lo bf16 out, layout [b][p][HID]
// ---------------------------------------------------------------------------
template <int C>
__global__ __launch_bounds__(256) void proj_kernel(
    const float* __restrict__ X, const float* __restrict__ W,
    const float* __restrict__ bias, ushort_t* __restrict__ Oh,
    ushort_t* __restrict__ Ol) {
  const int b = blockIdx.z;
  const int p0 = blockIdx.y * 64;
  const int o0 = blockIdx.x * 64;
  const int tid = threadIdx.x;
  const int lane = tid & 63;
  const int wave = tid >> 6;
  const int wm = wave & 1;
  const int wn = wave >> 1;
  const int l15 = lane & 15;
  const int quad = lane >> 4;

  __shared__ ushort_t Xh[64][40];
  __shared__ ushort_t Xl[64][40];

  f32x4 acc[2][2] = {};
  const float* Xb = X + (size_t)b * C * PP;
  const int cc = tid >> 3;
  const int ppo = (tid & 7) * 8;

  for (int c0 = 0; c0 < C; c0 += 32) {
    const float* src = Xb + (size_t)(c0 + cc) * PP + p0 + ppo;
    float4 v0 = *(const float4*)(src);
    float4 v1 = *(const float4*)(src + 4);
    float vv[8] = {v0.x, v0.y, v0.z, v0.w, v1.x, v1.y, v1.z, v1.w};
#pragma unroll
    for (int j = 0; j < 8; ++j) {
      unsigned short h = f2bf(vv[j]);
      Xh[ppo + j][cc] = h;
      Xl[ppo + j][cc] = f2bf(vv[j] - bf2f(h));
    }
    __syncthreads();

    bf16x8 wh[2], wl[2];
#pragma unroll
    for (int mt = 0; mt < 2; ++mt) {
      const float* wsrc =
          W + (size_t)(o0 + wm * 32 + mt * 16 + l15) * C + c0 + quad * 8;
      float4 a0 = *(const float4*)(wsrc);
      float4 a1 = *(const float4*)(wsrc + 4);
      float av[8] = {a0.x, a0.y, a0.z, a0.w, a1.x, a1.y, a1.z, a1.w};
      u16x8 hh, ll;
#pragma unroll
      for (int j = 0; j < 8; ++j) {
        unsigned short h = f2bf(av[j]);
        hh[j] = h;
        ll[j] = f2bf(av[j] - bf2f(h));
      }
      wh[mt] = __builtin_bit_cast(bf16x8, hh);
      wl[mt] = __builtin_bit_cast(bf16x8, ll);
    }

#pragma unroll
    for (int nt = 0; nt < 2; ++nt) {
      const int pr = wn * 32 + nt * 16 + l15;
      bf16x8 xh = load_bf8(&Xh[pr][quad * 8]);
      bf16x8 xl = load_bf8(&Xl[pr][quad * 8]);
#pragma unroll
      for (int mt = 0; mt < 2; ++mt) {
        acc[mt][nt] = MFMA16(wh[mt], xh, acc[mt][nt]);
        acc[mt][nt] = MFMA16(wl[mt], xh, acc[mt][nt]);
        acc[mt][nt] = MFMA16(wh[mt], xl, acc[mt][nt]);
      }
    }
    __syncthreads();
  }

#pragma unroll
  for (int mt = 0; mt < 2; ++mt) {
    const int ob = o0 + wm * 32 + mt * 16 + quad * 4;
#pragma unroll
    for (int nt = 0; nt < 2; ++nt) {
      const int p = p0 + wn * 32 + nt * 16 + l15;
      u16x4 hs, ls;
#pragma unroll
      for (int r = 0; r < 4; ++r) {
        float v = acc[mt][nt][r] + bias[ob + r];
        unsigned short h = f2bf(v);
        hs[r] = h;
        ls[r] = f2bf(v - bf2f(h));
      }
      const size_t base = ((size_t)b * PP + p) * HIDD + ob;
      *(u16x4*)(Oh + base) = hs;
      *(u16x4*)(Ol + base) = ls;
    }
  }
}

__global__ void cast_v_kernel(const float* __restrict__ X,
                              ushort_t* __restrict__ V) {
  const size_t i = ((size_t)blockIdx.x * 256 + threadIdx.x) * 4;
  float4 v = *(const float4*)(X + i);
  u16x4 o;
  o[0] = f2bf(v.x); o[1] = f2bf(v.y); o[2] = f2bf(v.z); o[3] = f2bf(v.w);
  *(u16x4*)(V + i) = o;
}

// ---------------------------------------------------------------------------
// Flash attention v4: wave-private softmax, async K staging, 1 barrier/tile.
// WG = 64 q-rows (wave owns 16). K-tile = 32 keys, hi/lo staged via
// global_load_lds into padded LDS (1040B row-pair pitch -> <=2-way banks).
// PV: each wave covers all 512 channels; V direct from global (L1 reuse).
// ---------------------------------------------------------------------------
template <bool DIRECT>
__global__ __launch_bounds__(256, 2) void attn4_kernel(
    const ushort_t* __restrict__ Qh, const ushort_t* __restrict__ Ql,
    const ushort_t* __restrict__ Kh, const ushort_t* __restrict__ Kl,
    const ushort_t* __restrict__ Vb, float* __restrict__ out,
    float* __restrict__ Opart, float* __restrict__ mlbuf, int kpc) {
  const int b = blockIdx.z;
  const int kc = blockIdx.y;
  const int qb = blockIdx.x;
  const int tid = threadIdx.x;
  const int lane = tid & 63;
  const int w = tid >> 6;
  const int l15 = lane & 15;
  const int quad = lane >> 4;
  const int k0 = kc * kpc;
  const int ntiles = kpc / 32;

  // [dbuf][hl][row-pair][520 u16 = 1040 B]  (pad 16B per pair -> 2-way banks)
  __shared__ __align__(16) ushort_t Kbuf[2][2][16][520];
  __shared__ __align__(16) ushort_t P_lds[4][16][40];

  // ---- Q preload: wave's 16 q-rows, hi/lo (64 VGPRs) ----
  bf16x8 qh[8], ql[8];
  {
    const size_t qrow = ((size_t)b * PP + qb * 64 + w * 16 + l15) * HIDD;
#pragma unroll
    for (int ks = 0; ks < 8; ++ks) {
      qh[ks] = load_bf8(Qh + qrow + ks * 32 + quad * 8);
      ql[ks] = load_bf8(Ql + qrow + ks * 32 + quad * 8);
    }
  }

  f32x4 o_acc[32] = {};
  float m_run[4] = {-3.0e38f, -3.0e38f, -3.0e38f, -3.0e38f};
  float l_run[4] = {0.f, 0.f, 0.f, 0.f};

  const ushort_t* Kb[2] = {Kh + ((size_t)b * PP + k0) * HIDD,
                           Kl + ((size_t)b * PP + k0) * HIDD};
  const ushort_t* vbase = Vb + ((size_t)b * CRD + l15) * PP + k0 + quad * 8;

  // stage tile t into buf: 32 x 1KB instrs split 8 per wave
  auto stage = [&](int t, int buf) {
#pragma unroll
    for (int j = 0; j < 8; ++j) {
      const int idx = w * 8 + j;        // 0..31
      const int hl = idx >> 4;          // 0..1
      const int pair = idx & 15;        // 0..15
      const ushort_t* src =
          Kb[hl] + ((size_t)(t * 32 + pair * 2)) * HIDD + lane * 8;
      async16(src, &Kbuf[buf][hl][pair][0]);
    }
  };

  stage(0, 0);
  __syncthreads();

  for (int t = 0; t < ntiles; ++t) {
    const int buf = t & 1;
    if (t + 1 < ntiles) stage(t + 1, buf ^ 1);

    // ---- S phase: S[16q x 32k], 3-term split-bf16 ----
    f32x4 sa0 = {}, sa1 = {};
#pragma unroll
    for (int ks = 0; ks < 8; ++ks) {
      const int co = (l15 & 1) * 256 + ks * 32 + quad * 8;
      bf16x8 kh0 = load_bf8(&Kbuf[buf][0][(l15 >> 1)][co]);
      bf16x8 kl0 = load_bf8(&Kbuf[buf][1][(l15 >> 1)][co]);
      bf16x8 kh1 = load_bf8(&Kbuf[buf][0][8 + (l15 >> 1)][co]);
      bf16x8 kl1 = load_bf8(&Kbuf[buf][1][8 + (l15 >> 1)][co]);
      sa0 = MFMA16(qh[ks], kh0, sa0);
      sa1 = MFMA16(qh[ks], kh1, sa1);
      sa0 = MFMA16(ql[ks], kh0, sa0);
      sa1 = MFMA16(ql[ks], kh1, sa1);
      sa0 = MFMA16(qh[ks], kl0, sa0);
      sa1 = MFMA16(qh[ks], kl1, sa1);
    }

    // ---- wave-private online softmax (rows = quad*4+r) ----
    float mx[4], al[4], p0[4], p1[4], rs[4];
#pragma unroll
    for (int r = 0; r < 4; ++r) mx[r] = fmaxf(sa0[r], sa1[r]);
#pragma unroll
    for (int d = 1; d < 16; d <<= 1)
#pragma unroll
      for (int r = 0; r < 4; ++r) mx[r] = fmaxf(mx[r], __shfl_xor(mx[r], d));
#pragma unroll
    for (int r = 0; r < 4; ++r) {
      const float mnew = fmaxf(m_run[r], mx[r]);
      al[r] = __expf(m_run[r] - mnew);
      m_run[r] = mnew;
      p0[r] = __expf(sa0[r] - mnew);
      p1[r] = __expf(sa1[r] - mnew);
      rs[r] = p0[r] + p1[r];
    }
#pragma unroll
    for (int d = 1; d < 16; d <<= 1)
#pragma unroll
      for (int r = 0; r < 4; ++r) rs[r] += __shfl_xor(rs[r], d);
#pragma unroll
    for (int r = 0; r < 4; ++r) l_run[r] = l_run[r] * al[r] + rs[r];

    // P -> per-wave LDS (C-layout scatter), read back as A-fragment
#pragma unroll
    for (int r = 0; r < 4; ++r) {
      P_lds[w][quad * 4 + r][l15] = f2bf(p0[r]);
      P_lds[w][quad * 4 + r][16 + l15] = f2bf(p1[r]);
    }
    asm volatile("s_waitcnt lgkmcnt(0)" ::: "memory");
    bf16x8 pa = load_bf8(&P_lds[w][l15][quad * 8]);

    // ---- rescale O, then PV over all 512 channels ----
#pragma unroll
    for (int nt = 0; nt < 32; ++nt)
#pragma unroll
      for (int r = 0; r < 4; ++r) o_acc[nt][r] *= al[r];

    const ushort_t* vt = vbase + t * 32;
#pragma unroll
    for (int nt = 0; nt < 32; ++nt) {
      bf16x8 vf = load_bf8(vt + (size_t)nt * 16 * PP);
      o_acc[nt] = MFMA16(pa, vf, o_acc[nt]);
    }

    __syncthreads();
  }

  // ---- epilogue ----
  if (DIRECT) {
    float rl[4];
#pragma unroll
    for (int r = 0; r < 4; ++r) rl[r] = 1.f / l_run[r];
    const int q0 = qb * 64 + w * 16 + quad * 4;
#pragma unroll
    for (int nt = 0; nt < 32; ++nt) {
      const int c = nt * 16 + l15;
      float* op = out + ((size_t)b * CRD + c) * PP + q0;
#pragma unroll
      for (int r = 0; r < 4; ++r) op[r] = o_acc[nt][r] * rl[r];
    }
  } else {
    const size_t cidx = ((size_t)kc * BB + b) * NQB + qb;
    float* opb = Opart + cidx * (64 * 512);
    const int qrow = w * 16 + quad * 4;
#pragma unroll
    for (int nt = 0; nt < 32; ++nt) {
      const int c = nt * 16 + l15;
#pragma unroll
      for (int r = 0; r < 4; ++r) opb[(size_t)(qrow + r) * 512 + c] = o_acc[nt][r];
    }
    if (l15 == 0) {
#pragma unroll
      for (int r = 0; r < 4; ++r) {
        mlbuf[cidx * 128 + qrow + r] = m_run[r];
        mlbuf[cidx * 128 + 64 + qrow + r] = l_run[r];
      }
    }
  }
}

// ---------------------------------------------------------------------------
// Combine KC=2 partials -> fp32 out[b][c][p]
// ---------------------------------------------------------------------------
__global__ __launch_bounds__(256) void combine4_kernel(
    const float* __restrict__ Opart, const float* __restrict__ mlbuf,
    float* __restrict__ out) {
  const int qb = blockIdx.x;
  const int b = blockIdx.y;
  const int tid = threadIdx.x;
  const int q4 = (tid >> 4) * 4;  // 0..60
  const int cl = tid & 15;

  const size_t c0 = ((size_t)0 * BB + b) * NQB + qb;
  const size_t c1 = ((size_t)1 * BB + b) * NQB + qb;
  const float* op0 = Opart + c0 * (64 * 512);
  const float* op1 = Opart + c1 * (64 * 512);

  float w0[4], w1[4];
#pragma unroll
  for (int r = 0; r < 4; ++r) {
    const int q = q4 + r;
    const float m0 = mlbuf[c0 * 128 + q], l0 = mlbuf[c0 * 128 + 64 + q];
    const float m1 = mlbuf[c1 * 128 + q], l1 = mlbuf[c1 * 128 + 64 + q];
    const float M = fmaxf(m0, m1);
    const float a0 = __expf(m0 - M), a1 = __expf(m1 - M);
    const float inv = 1.f / (a0 * l0 + a1 * l1);
    w0[r] = a0 * inv;
    w1[r] = a1 * inv;
  }

  for (int i = 0; i < 32; ++i) {
    const int c = cl + 16 * i;
    f32x4 v;
#pragma unroll
    for (int r = 0; r < 4; ++r)
      v[r] = w0[r] * op0[(size_t)(q4 + r) * 512 + c] +
             w1[r] * op1[(size_t)(q4 + r) * 512 + c];
    *(f32x4*)(out + ((size_t)b * CRD + c) * PP + qb * 64 + q4) = v;
  }
}

// ---------------------------------------------------------------------------
extern "C" void kernel_launch(void* const* d_in, const int* in_sizes, int n_in,
                              void* d_out, int out_size, void* d_ws,
                              size_t ws_size, hipStream_t stream) {
  (void)in_sizes; (void)n_in; (void)out_size;

  const float* Xq = (const float*)d_in[0];
  const float* Xr = (const float*)d_in[1];
  const float* Wq = (const float*)d_in[2];
  const float* bq = (const float*)d_in[3];
  const float* Wk = (const float*)d_in[4];
  const float* bk = (const float*)d_in[5];
  float* out = (float*)d_out;

  const size_t nQK = (size_t)BB * PP * HIDD;  // 4.72M elems
  const size_t nV = (size_t)BB * CRD * PP;    // 9.44M elems

  ushort_t* p = (ushort_t*)d_ws;
  ushort_t* Qh = p; p += nQK;
  ushort_t* Ql = p; p += nQK;
  ushort_t* Kh = p; p += nQK;
  ushort_t* Kl = p; p += nQK;
  ushort_t* Vb = p; p += nV;
  float* Opart = (float*)p;                   // KC*8*36*64*512 f32 = 75.5 MB
  float* mlbuf = Opart + (size_t)KC * BB * NQB * 64 * 512;
  const size_t needed = (size_t)((char*)(mlbuf + (size_t)KC * BB * NQB * 128) -
                                 (char*)d_ws);

  proj_kernel<CQD><<<dim3(4, PP / 64, BB), 256, 0, stream>>>(Xq, Wq, bq, Qh, Ql);
  proj_kernel<CRD><<<dim3(4, PP / 64, BB), 256, 0, stream>>>(Xr, Wk, bk, Kh, Kl);
  cast_v_kernel<<<dim3(nV / 1024), 256, 0, stream>>>(Xr, Vb);

  if (ws_size >= needed) {
    attn4_kernel<false><<<dim3(NQB, KC, BB), 256, 0, stream>>>(
        Qh, Ql, Kh, Kl, Vb, out, Opart, mlbuf, KPC);
    combine4_kernel<<<dim3(NQB, BB), 256, 0, stream>>>(Opart, mlbuf, out);
  } else {
    attn4_kernel<true><<<dim3(NQB, 1, BB), 256, 0, stream>>>(
        Qh, Ql, Kh, Kl, Vb, out, (float*)Qh, (float*)Qh, PP);
  }
}

// Round 5
// 662.730 us; speedup vs baseline: 1.7938x; 1.6972x over previous
//
#include <hip/hip_runtime.h>

// (B, CQ, CR, HID, H, W) = (8, 1024, 512, 256, 48, 48)
#define BB   8
#define PP   2304
#define CQD  1024
#define CRD  512
#define HIDD 256
#define GB   4       // batches per group (S scratch reuse)
#define NKB  36      // 64-key stat blocks per row
#define LOG2E 1.4426950408889634f

typedef float f32x4 __attribute__((ext_vector_type(4)));
typedef __bf16 bf16x8 __attribute__((ext_vector_type(8)));
typedef unsigned short u16x8 __attribute__((ext_vector_type(8)));
typedef unsigned short u16x4 __attribute__((ext_vector_type(4)));
typedef unsigned int u32x4 __attribute__((ext_vector_type(4)));
typedef unsigned short ushort_t;

__device__ __forceinline__ unsigned short f2bf(float f) {
  unsigned int u = __float_as_uint(f);
  u += 0x7fffu + ((u >> 16) & 1u);  // RNE
  return (unsigned short)(u >> 16);
}
__device__ __forceinline__ float bf2f(unsigned short h) {
  return __uint_as_float(((unsigned int)h) << 16);
}
__device__ __forceinline__ bf16x8 load_bf8(const ushort_t* p) {
  return *(const bf16x8*)p;
}
__device__ __forceinline__ void async16(const void* g, void* l) {
  __builtin_amdgcn_global_load_lds(
      (const __attribute__((address_space(1))) unsigned int*)g,
      (__attribute__((address_space(3))) unsigned int*)l, 16, 0, 0);
}

#define MFMA16(a, b, c) __builtin_amdgcn_mfma_f32_16x16x32_bf16((a), (b), (c), 0, 0, 0)

// ---------------------------------------------------------------------------
// Projection (round-1, measured): Out[b][p][o] = sum_c W[o][c] X[b][c][p] + b
// ---------------------------------------------------------------------------
template <int C>
__global__ __launch_bounds__(256) void proj_kernel(
    const float* __restrict__ X, const float* __restrict__ W,
    const float* __restrict__ bias, ushort_t* __restrict__ Oh,
    ushort_t* __restrict__ Ol) {
  const int b = blockIdx.z;
  const int p0 = blockIdx.y * 64;
  const int o0 = blockIdx.x * 64;
  const int tid = threadIdx.x;
  const int lane = tid & 63;
  const int wave = tid >> 6;
  const int wm = wave & 1;
  const int wn = wave >> 1;
  const int l15 = lane & 15;
  const int quad = lane >> 4;

  __shared__ ushort_t Xh[64][40];
  __shared__ ushort_t Xl[64][40];

  f32x4 acc[2][2] = {};
  const float* Xb = X + (size_t)b * C * PP;
  const int cc = tid >> 3;
  const int ppo = (tid & 7) * 8;

  for (int c0 = 0; c0 < C; c0 += 32) {
    const float* src = Xb + (size_t)(c0 + cc) * PP + p0 + ppo;
    float4 v0 = *(const float4*)(src);
    float4 v1 = *(const float4*)(src + 4);
    float vv[8] = {v0.x, v0.y, v0.z, v0.w, v1.x, v1.y, v1.z, v1.w};
#pragma unroll
    for (int j = 0; j < 8; ++j) {
      unsigned short h = f2bf(vv[j]);
      Xh[ppo + j][cc] = h;
      Xl[ppo + j][cc] = f2bf(vv[j] - bf2f(h));
    }
    __syncthreads();

    bf16x8 wh[2], wl[2];
#pragma unroll
    for (int mt = 0; mt < 2; ++mt) {
      const float* wsrc =
          W + (size_t)(o0 + wm * 32 + mt * 16 + l15) * C + c0 + quad * 8;
      float4 a0 = *(const float4*)(wsrc);
      float4 a1 = *(const float4*)(wsrc + 4);
      float av[8] = {a0.x, a0.y, a0.z, a0.w, a1.x, a1.y, a1.z, a1.w};
      u16x8 hh, ll;
#pragma unroll
      for (int j = 0; j < 8; ++j) {
        unsigned short h = f2bf(av[j]);
        hh[j] = h;
        ll[j] = f2bf(av[j] - bf2f(h));
      }
      wh[mt] = __builtin_bit_cast(bf16x8, hh);
      wl[mt] = __builtin_bit_cast(bf16x8, ll);
    }

#pragma unroll
    for (int nt = 0; nt < 2; ++nt) {
      const int pr = wn * 32 + nt * 16 + l15;
      bf16x8 xh = load_bf8(&Xh[pr][quad * 8]);
      bf16x8 xl = load_bf8(&Xl[pr][quad * 8]);
#pragma unroll
      for (int mt = 0; mt < 2; ++mt) {
        acc[mt][nt] = MFMA16(wh[mt], xh, acc[mt][nt]);
        acc[mt][nt] = MFMA16(wl[mt], xh, acc[mt][nt]);
        acc[mt][nt] = MFMA16(wh[mt], xl, acc[mt][nt]);
      }
    }
    __syncthreads();
  }

#pragma unroll
  for (int mt = 0; mt < 2; ++mt) {
    const int ob = o0 + wm * 32 + mt * 16 + quad * 4;
#pragma unroll
    for (int nt = 0; nt < 2; ++nt) {
      const int p = p0 + wn * 32 + nt * 16 + l15;
      u16x4 hs, ls;
#pragma unroll
      for (int r = 0; r < 4; ++r) {
        float v = acc[mt][nt][r] + bias[ob + r];
        unsigned short h = f2bf(v);
        hs[r] = h;
        ls[r] = f2bf(v - bf2f(h));
      }
      const size_t base = ((size_t)b * PP + p) * HIDD + ob;
      *(u16x4*)(Oh + base) = hs;
      *(u16x4*)(Ol + base) = ls;
    }
  }
}

__global__ void cast_v_kernel(const float* __restrict__ X,
                              ushort_t* __restrict__ V) {
  const size_t i = ((size_t)blockIdx.x * 256 + threadIdx.x) * 4;
  float4 v = *(const float4*)(X + i);
  u16x4 o;
  o[0] = f2bf(v.x); o[1] = f2bf(v.y); o[2] = f2bf(v.z); o[3] = f2bf(v.w);
  *(u16x4*)(V + i) = o;
}

// ---------------------------------------------------------------------------
// S-GEMM: S[b][q][k] = sum_h Q[q][h]*K[k][h]  (3-term split-bf16, fp32 out)
// 128x128 WG tile, wave = 64x64 quadrant, 4x4 accs. Epilogue: per-64-key-block
// row stats (max, sum exp) -> mpart/lpart.
// ---------------------------------------------------------------------------
__global__ __launch_bounds__(256, 2) void sgemm_kernel(
    const ushort_t* __restrict__ Qh, const ushort_t* __restrict__ Ql,
    const ushort_t* __restrict__ Kh, const ushort_t* __restrict__ Kl,
    float* __restrict__ Sbuf, float* __restrict__ mpart,
    float* __restrict__ lpart, int bbase) {
  const int b = blockIdx.z;  // batch within group
  const int gb = bbase + b;
  const int q0 = blockIdx.x * 128;
  const int k0 = blockIdx.y * 128;
  const int tid = threadIdx.x;
  const int lane = tid & 63;
  const int w = tid >> 6;
  const int l15 = lane & 15;
  const int quad = lane >> 4;
  const int wm = w & 1;
  const int wn = w >> 1;

  // [buf][tensor 0=Ah 1=Al 2=Bh 3=Bl][row][col]  (packed; 64 KB total)
  __shared__ __align__(16) ushort_t AB[2][4][128][32];

  f32x4 acc[4][4] = {};

  const ushort_t* srcs[4] = {Qh + ((size_t)gb * PP + q0) * HIDD,
                             Ql + ((size_t)gb * PP + q0) * HIDD,
                             Kh + ((size_t)gb * PP + k0) * HIDD,
                             Kl + ((size_t)gb * PP + k0) * HIDD};
  const ushort_t* mysrc = srcs[w];
  const int r16 = lane >> 2;       // row-in-16-group
  const int c8 = (lane & 3) * 8;   // u16 col offset

  // wave w stages tensor w: 8 async16 per kstep
  auto stage = [&](int cs, int buf) {
    const ushort_t* sp = mysrc + cs * 32 + c8;
#pragma unroll
    for (int i = 0; i < 8; ++i)
      async16(sp + (size_t)(i * 16 + r16) * HIDD, &AB[buf][w][i * 16][0]);
  };

  stage(0, 0);
  __syncthreads();

  for (int cs = 0; cs < 8; ++cs) {
    const int buf = cs & 1;
    if (cs + 1 < 8) stage(cs + 1, buf ^ 1);

    bf16x8 ah[4], al[4], bh[4], bl[4];
#pragma unroll
    for (int mt = 0; mt < 4; ++mt) {
      const int row = wm * 64 + mt * 16 + l15;
      ah[mt] = load_bf8(&AB[buf][0][row][quad * 8]);
      al[mt] = load_bf8(&AB[buf][1][row][quad * 8]);
    }
#pragma unroll
    for (int nt = 0; nt < 4; ++nt) {
      const int row = wn * 64 + nt * 16 + l15;
      bh[nt] = load_bf8(&AB[buf][2][row][quad * 8]);
      bl[nt] = load_bf8(&AB[buf][3][row][quad * 8]);
    }
#pragma unroll
    for (int mt = 0; mt < 4; ++mt)
#pragma unroll
      for (int nt = 0; nt < 4; ++nt) {
        acc[mt][nt] = MFMA16(ah[mt], bh[nt], acc[mt][nt]);
        acc[mt][nt] = MFMA16(al[mt], bh[nt], acc[mt][nt]);
        acc[mt][nt] = MFMA16(ah[mt], bl[nt], acc[mt][nt]);
      }
    __syncthreads();
  }

  // ---- epilogue: per-row 64-key-block stats + S store ----
  const int kb = blockIdx.y * 2 + wn;
#pragma unroll
  for (int mt = 0; mt < 4; ++mt) {
#pragma unroll
    for (int r = 0; r < 4; ++r) {
      float m = fmaxf(fmaxf(acc[mt][0][r], acc[mt][1][r]),
                      fmaxf(acc[mt][2][r], acc[mt][3][r]));
      m = fmaxf(m, __shfl_xor(m, 1));
      m = fmaxf(m, __shfl_xor(m, 2));
      m = fmaxf(m, __shfl_xor(m, 4));
      m = fmaxf(m, __shfl_xor(m, 8));
      float e = __expf(acc[mt][0][r] - m) + __expf(acc[mt][1][r] - m) +
                __expf(acc[mt][2][r] - m) + __expf(acc[mt][3][r] - m);
      e += __shfl_xor(e, 1);
      e += __shfl_xor(e, 2);
      e += __shfl_xor(e, 4);
      e += __shfl_xor(e, 8);
      if (l15 == 0) {
        const int q = q0 + wm * 64 + mt * 16 + quad * 4 + r;
        mpart[((size_t)b * NKB + kb) * PP + q] = m;
        lpart[((size_t)b * NKB + kb) * PP + q] = e;
      }
    }
  }
#pragma unroll
  for (int mt = 0; mt < 4; ++mt) {
#pragma unroll
    for (int nt = 0; nt < 4; ++nt) {
      const int k = k0 + wn * 64 + nt * 16 + l15;
#pragma unroll
      for (int r = 0; r < 4; ++r) {
        const int q = q0 + wm * 64 + mt * 16 + quad * 4 + r;
        Sbuf[((size_t)b * PP + q) * PP + k] = acc[mt][nt][r];
      }
    }
  }
}

// ---------------------------------------------------------------------------
// Stats reduce: C[b][q] = M*log2e + log2(L)  so that  exp(s-M)/L =
// exp2(s*log2e - C).
// ---------------------------------------------------------------------------
__global__ __launch_bounds__(256) void stats_kernel(
    const float* __restrict__ mpart, const float* __restrict__ lpart,
    float* __restrict__ Crow) {
  const int q = blockIdx.x * 256 + threadIdx.x;
  const int b = blockIdx.y;
  float m[NKB];
  float M = -3.0e38f;
#pragma unroll
  for (int kb = 0; kb < NKB; ++kb) {
    m[kb] = mpart[((size_t)b * NKB + kb) * PP + q];
    M = fmaxf(M, m[kb]);
  }
  float L = 0.f;
#pragma unroll
  for (int kb = 0; kb < NKB; ++kb)
    L += __expf(m[kb] - M) * lpart[((size_t)b * NKB + kb) * PP + q];
  Crow[(size_t)b * PP + q] = M * LOG2E + __builtin_log2f(L);
}

// ---------------------------------------------------------------------------
// PV-GEMM: out[gb][c][q] = sum_k exp2(S[q][k]*log2e - C[q]) * V[c][k]
// WG tile 64q x 128c; wave = 32q x 64c (2x4 accs). A (S fp32) staged with
// XOR-chunk swizzle (bank-balanced); V staged packed. 72-step K loop.
// ---------------------------------------------------------------------------
__global__ __launch_bounds__(256, 2) void pv_kernel(
    const float* __restrict__ Sbuf, const ushort_t* __restrict__ Vb,
    const float* __restrict__ Crow, float* __restrict__ out, int bbase) {
  const int b = blockIdx.z;
  const int gb = bbase + b;
  const int m0 = blockIdx.x * 64;   // q
  const int n0 = blockIdx.y * 128;  // channel
  const int tid = threadIdx.x;
  const int lane = tid & 63;
  const int w = tid >> 6;
  const int l15 = lane & 15;
  const int quad = lane >> 4;
  const int wm = w & 1;
  const int wn = w >> 1;

  __shared__ __align__(16) float Asw[2][64][32];     // 16 KB (chunk-swizzled)
  __shared__ __align__(16) ushort_t Vt[2][128][32];  // 16 KB

  f32x4 acc[2][4] = {};

  const float* Sb_base = Sbuf + ((size_t)b * PP + m0) * PP;
  const ushort_t* V_base = Vb + ((size_t)gb * CRD + n0) * PP;

  int rb[2];
  float C2[2];
#pragma unroll
  for (int mt = 0; mt < 2; ++mt) {
    const int row = wm * 32 + mt * 16 + l15;
    rb[mt] = row & 7;
    C2[mt] = Crow[(size_t)b * PP + m0 + row];
  }

  const int ar = lane >> 3, ac = lane & 7;   // A staging: 8 rows x 8 chunks
  const int vr = lane >> 2, vc = lane & 3;   // V staging: 16 rows x 4 chunks

  auto stage = [&](int kt, int buf) {
#pragma unroll
    for (int j = 0; j < 2; ++j) {
      const int i = w * 2 + j;
      const int row = i * 8 + ar;
      const int c = ac ^ (row & 7);  // XOR swizzle on 16B chunks
      async16(Sb_base + (size_t)row * PP + kt * 32 + c * 4,
              &Asw[buf][i * 8][0]);
    }
#pragma unroll
    for (int j = 0; j < 2; ++j) {
      const int i = w * 2 + j;
      const int row = i * 16 + vr;
      async16(V_base + (size_t)row * PP + kt * 32 + vc * 8,
              &Vt[buf][i * 16][0]);
    }
  };

  stage(0, 0);
  __syncthreads();

  for (int kt = 0; kt < PP / 32; ++kt) {
    const int buf = kt & 1;
    if (kt + 1 < PP / 32) stage(kt + 1, buf ^ 1);

    bf16x8 pa[2];
#pragma unroll
    for (int mt = 0; mt < 2; ++mt) {
      const int row = wm * 32 + mt * 16 + l15;
      f32x4 a0 = *(const f32x4*)&Asw[buf][row][((quad * 2) ^ rb[mt]) * 4];
      f32x4 a1 = *(const f32x4*)&Asw[buf][row][((quad * 2 + 1) ^ rb[mt]) * 4];
      float s8[8] = {a0[0], a0[1], a0[2], a0[3], a1[0], a1[1], a1[2], a1[3]};
      u32x4 bits;
#pragma unroll
      for (int j = 0; j < 4; ++j) {
        float e0 = __builtin_exp2f(fmaf(s8[2 * j], LOG2E, -C2[mt]));
        float e1 = __builtin_exp2f(fmaf(s8[2 * j + 1], LOG2E, -C2[mt]));
        bits[j] = (unsigned int)f2bf(e0) | ((unsigned int)f2bf(e1) << 16);
      }
      pa[mt] = __builtin_bit_cast(bf16x8, bits);
    }

    bf16x8 vf[4];
#pragma unroll
    for (int nt = 0; nt < 4; ++nt)
      vf[nt] = load_bf8(&Vt[buf][wn * 64 + nt * 16 + l15][quad * 8]);

#pragma unroll
    for (int mt = 0; mt < 2; ++mt)
#pragma unroll
      for (int nt = 0; nt < 4; ++nt)
        acc[mt][nt] = MFMA16(pa[mt], vf[nt], acc[mt][nt]);

    __syncthreads();
  }

  // epilogue: already normalized (1/L folded into exp). out[gb][c][q].
#pragma unroll
  for (int mt = 0; mt < 2; ++mt) {
    const int q = m0 + wm * 32 + mt * 16 + quad * 4;
#pragma unroll
    for (int nt = 0; nt < 4; ++nt) {
      const int ch = n0 + wn * 64 + nt * 16 + l15;
      *(f32x4*)(out + ((size_t)gb * CRD + ch) * PP + q) = acc[mt][nt];
    }
  }
}

// ---------------------------------------------------------------------------
// Fallback fused attention (round-3 DIRECT) for small workspaces.
// ---------------------------------------------------------------------------
__global__ __launch_bounds__(256, 2) void attn_direct_kernel(
    const ushort_t* __restrict__ Qh, const ushort_t* __restrict__ Ql,
    const ushort_t* __restrict__ Kh, const ushort_t* __restrict__ Kl,
    const ushort_t* __restrict__ Vb, float* __restrict__ out) {
  const int b = blockIdx.z;
  const int qb = blockIdx.x;
  const int tid = threadIdx.x;
  const int lane = tid & 63;
  const int w = tid >> 6;
  const int l15 = lane & 15;
  const int quad = lane >> 4;

  __shared__ __align__(16) ushort_t Kbuf[2][2][16][520];
  __shared__ __align__(16) ushort_t P_lds[4][16][40];

  bf16x8 qh[8], ql[8];
  {
    const size_t qrow = ((size_t)b * PP + qb * 64 + w * 16 + l15) * HIDD;
#pragma unroll
    for (int ks = 0; ks < 8; ++ks) {
      qh[ks] = load_bf8(Qh + qrow + ks * 32 + quad * 8);
      ql[ks] = load_bf8(Ql + qrow + ks * 32 + quad * 8);
    }
  }

  f32x4 o_acc[32] = {};
  float m_run[4] = {-3.0e38f, -3.0e38f, -3.0e38f, -3.0e38f};
  float l_run[4] = {0.f, 0.f, 0.f, 0.f};

  const ushort_t* Kb[2] = {Kh + (size_t)b * PP * HIDD,
                           Kl + (size_t)b * PP * HIDD};
  const ushort_t* vbase = Vb + ((size_t)b * CRD + l15) * PP + quad * 8;

  auto stage = [&](int t, int buf) {
#pragma unroll
    for (int j = 0; j < 8; ++j) {
      const int idx = w * 8 + j;
      const int hl = idx >> 4;
      const int pair = idx & 15;
      const ushort_t* src =
          Kb[hl] + ((size_t)(t * 32 + pair * 2)) * HIDD + lane * 8;
      async16(src, &Kbuf[buf][hl][pair][0]);
    }
  };

  stage(0, 0);
  __syncthreads();

  for (int t = 0; t < PP / 32; ++t) {
    const int buf = t & 1;
    if (t + 1 < PP / 32) stage(t + 1, buf ^ 1);

    f32x4 sa0 = {}, sa1 = {};
#pragma unroll
    for (int ks = 0; ks < 8; ++ks) {
      const int co = (l15 & 1) * 256 + ks * 32 + quad * 8;
      bf16x8 kh0 = load_bf8(&Kbuf[buf][0][(l15 >> 1)][co]);
      bf16x8 kl0 = load_bf8(&Kbuf[buf][1][(l15 >> 1)][co]);
      bf16x8 kh1 = load_bf8(&Kbuf[buf][0][8 + (l15 >> 1)][co]);
      bf16x8 kl1 = load_bf8(&Kbuf[buf][1][8 + (l15 >> 1)][co]);
      sa0 = MFMA16(qh[ks], kh0, sa0);
      sa1 = MFMA16(qh[ks], kh1, sa1);
      sa0 = MFMA16(ql[ks], kh0, sa0);
      sa1 = MFMA16(ql[ks], kh1, sa1);
      sa0 = MFMA16(qh[ks], kl0, sa0);
      sa1 = MFMA16(qh[ks], kl1, sa1);
    }

    float mx[4], al[4], p0[4], p1[4], rs[4];
#pragma unroll
    for (int r = 0; r < 4; ++r) mx[r] = fmaxf(sa0[r], sa1[r]);
#pragma unroll
    for (int d = 1; d < 16; d <<= 1)
#pragma unroll
      for (int r = 0; r < 4; ++r) mx[r] = fmaxf(mx[r], __shfl_xor(mx[r], d));
#pragma unroll
    for (int r = 0; r < 4; ++r) {
      const float mnew = fmaxf(m_run[r], mx[r]);
      al[r] = __expf(m_run[r] - mnew);
      m_run[r] = mnew;
      p0[r] = __expf(sa0[r] - mnew);
      p1[r] = __expf(sa1[r] - mnew);
      rs[r] = p0[r] + p1[r];
    }
#pragma unroll
    for (int d = 1; d < 16; d <<= 1)
#pragma unroll
      for (int r = 0; r < 4; ++r) rs[r] += __shfl_xor(rs[r], d);
#pragma unroll
    for (int r = 0; r < 4; ++r) l_run[r] = l_run[r] * al[r] + rs[r];

#pragma unroll
    for (int r = 0; r < 4; ++r) {
      P_lds[w][quad * 4 + r][l15] = f2bf(p0[r]);
      P_lds[w][quad * 4 + r][16 + l15] = f2bf(p1[r]);
    }
    asm volatile("s_waitcnt lgkmcnt(0)" ::: "memory");
    bf16x8 pa = load_bf8(&P_lds[w][l15][quad * 8]);

#pragma unroll
    for (int nt = 0; nt < 32; ++nt)
#pragma unroll
      for (int r = 0; r < 4; ++r) o_acc[nt][r] *= al[r];

    const ushort_t* vt = vbase + t * 32;
#pragma unroll
    for (int nt = 0; nt < 32; ++nt) {
      bf16x8 vfr = load_bf8(vt + (size_t)nt * 16 * PP);
      o_acc[nt] = MFMA16(pa, vfr, o_acc[nt]);
    }
    __syncthreads();
  }

  float rl[4];
#pragma unroll
  for (int r = 0; r < 4; ++r) rl[r] = 1.f / l_run[r];
  const int q0 = qb * 64 + w * 16 + quad * 4;
#pragma unroll
  for (int nt = 0; nt < 32; ++nt) {
    const int c = nt * 16 + l15;
    float* op = out + ((size_t)b * CRD + c) * PP + q0;
#pragma unroll
    for (int r = 0; r < 4; ++r) op[r] = o_acc[nt][r] * rl[r];
  }
}

// ---------------------------------------------------------------------------
extern "C" void kernel_launch(void* const* d_in, const int* in_sizes, int n_in,
                              void* d_out, int out_size, void* d_ws,
                              size_t ws_size, hipStream_t stream) {
  (void)in_sizes; (void)n_in; (void)out_size;

  const float* Xq = (const float*)d_in[0];
  const float* Xr = (const float*)d_in[1];
  const float* Wq = (const float*)d_in[2];
  const float* bq = (const float*)d_in[3];
  const float* Wk = (const float*)d_in[4];
  const float* bk = (const float*)d_in[5];
  float* out = (float*)d_out;

  const size_t nQK = (size_t)BB * PP * HIDD;  // 4.72M elems
  const size_t nV = (size_t)BB * CRD * PP;    // 9.44M elems

  ushort_t* p = (ushort_t*)d_ws;
  ushort_t* Qh = p; p += nQK;
  ushort_t* Ql = p; p += nQK;
  ushort_t* Kh = p; p += nQK;
  ushort_t* Kl = p; p += nQK;
  ushort_t* Vb = p; p += nV;
  float* Sbuf = (float*)p;                       // GB*2304*2304 f32 = 84.9 MB
  float* mpart = Sbuf + (size_t)GB * PP * PP;    // GB*36*2304
  float* lpart = mpart + (size_t)GB * NKB * PP;
  float* Crow = lpart + (size_t)GB * NKB * PP;   // GB*2304
  const size_t needed =
      (size_t)((char*)(Crow + (size_t)GB * PP) - (char*)d_ws);

  proj_kernel<CQD><<<dim3(4, PP / 64, BB), 256, 0, stream>>>(Xq, Wq, bq, Qh, Ql);
  proj_kernel<CRD><<<dim3(4, PP / 64, BB), 256, 0, stream>>>(Xr, Wk, bk, Kh, Kl);
  cast_v_kernel<<<dim3(nV / 1024), 256, 0, stream>>>(Xr, Vb);

  if (ws_size >= needed) {
    for (int g = 0; g < BB / GB; ++g) {
      const int bbase = g * GB;
      sgemm_kernel<<<dim3(PP / 128, PP / 128, GB), 256, 0, stream>>>(
          Qh, Ql, Kh, Kl, Sbuf, mpart, lpart, bbase);
      stats_kernel<<<dim3(PP / 256, GB), 256, 0, stream>>>(mpart, lpart, Crow);
      pv_kernel<<<dim3(PP / 64, CRD / 128, GB), 256, 0, stream>>>(
          Sbuf, Vb, Crow, out, bbase);
    }
  } else {
    attn_direct_kernel<<<dim3(PP / 64, 1, BB), 256, 0, stream>>>(
        Qh, Ql, Kh, Kl, Vb, out);
  }
}